// Round 18
// baseline (469.638 us; speedup 1.0000x reference)
//
#include <hip/hip_runtime.h>

#define NN 200000
#define NE 4000000
#define FIN 64
#define DIM 20
#define NGR 512
#define NCL 2
#define BN_EPS 1e-5f

#define BKT 391                 // buckets of 512 nodes (dst>>9)
#define BNODE 512
#define NCTR (8 * BKT)
#define T2 32768
#define NT2 ((NE + T2 - 1) / T2)   // 123
#define NSLC 4
#define SLCW 50000              // src-slice width

typedef unsigned short ushort_t;

__device__ __forceinline__ ushort_t f2bf(float f) {   // RNE bf16
    unsigned u = __float_as_uint(f);
    unsigned r = (u + 0x7fffu + ((u >> 16) & 1u)) >> 16;
    return (ushort_t)r;
}

// 20 bf16 feats split: yA[n] = 32B (feats 0..15), yB[n] = 8B (feats 16..19)
__device__ __forceinline__ void acc10(const uint4& a, const uint4& b, const uint2& c, float* acc) {
    unsigned u[10] = {a.x, a.y, a.z, a.w, b.x, b.y, b.z, b.w, c.x, c.y};
    #pragma unroll
    for (int i = 0; i < 10; ++i) {
        acc[2 * i]     += __uint_as_float(u[i] << 16);
        acc[2 * i + 1] += __uint_as_float(u[i] & 0xffff0000u);
    }
}

__device__ __forceinline__ void row_load_plain(const ushort_t* yA, const ushort_t* yB, int s,
                                               uint4& ra, uint4& rb, uint2& rc) {
    const uint4* pa = (const uint4*)(yA + (size_t)s * 16);
    ra = pa[0];
    rb = pa[1];
    rc = *(const uint2*)(yB + (size_t)s * 4);
}

// asm row load: 3 opaque loads -> results pinned in VGPRs until the waitcnt
__device__ __forceinline__ void row_load_asm(const ushort_t* yA, const ushort_t* yB, int s,
                                             uint4& ra, uint4& rb, uint2& rc) {
    unsigned long long apA = (unsigned long long)(yA + (size_t)s * 16);
    unsigned long long apB = (unsigned long long)(yB + (size_t)s * 4);
    asm volatile("global_load_dwordx4 %0, %1, off"           : "=v"(ra) : "v"(apA));
    asm volatile("global_load_dwordx4 %0, %1, off offset:16" : "=v"(rb) : "v"(apA));
    asm volatile("global_load_dwordx2 %0, %1, off"           : "=v"(rc) : "v"(apB));
}

__device__ __forceinline__ void nt_store4(float* p, float a, float b, float c, float d) {
    __builtin_nontemporal_store(a, p);
    __builtin_nontemporal_store(b, p + 1);
    __builtin_nontemporal_store(c, p + 2);
    __builtin_nontemporal_store(d, p + 3);
}

// ---------------- pass 1: per-(xcd,bucket) edge histogram ----------------
__global__ __launch_bounds__(256) void hist_kernel(const int* __restrict__ dst, int* __restrict__ ghist) {
    __shared__ int h[BKT];
    int t = threadIdx.x;
    for (int i = t; i < BKT; i += 256) h[i] = 0;
    __syncthreads();
    size_t base = (size_t)blockIdx.x * T2;
    for (int kk = 0; kk < 32; ++kk) {
        size_t e = base + (size_t)kk * 1024 + t * 4;
        if (e + 4 <= NE) {
            int4 d = *(const int4*)(dst + e);
            atomicAdd(&h[d.x >> 9], 1);
            atomicAdd(&h[d.y >> 9], 1);
            atomicAdd(&h[d.z >> 9], 1);
            atomicAdd(&h[d.w >> 9], 1);
        } else {
            for (int j = 0; j < 4; ++j)
                if (e + j < NE) atomicAdd(&h[dst[e + j] >> 9], 1);
        }
    }
    __syncthreads();
    int r = blockIdx.x & 7;
    for (int i = t; i < BKT; i += 256)
        if (h[i]) atomicAdd(&ghist[r * BKT + i], h[i]);
}

// ---------------- pass 2: scan 3128 counters ----------------
__global__ __launch_bounds__(1024) void scan_small_kernel(const int* __restrict__ ghist,
                                                          int* __restrict__ bbase, int* __restrict__ bcur) {
    __shared__ int c[1024];
    int t = threadIdx.x;
    int v[4];
    int sum = 0;
    #pragma unroll
    for (int j = 0; j < 4; ++j) {
        int idx = t * 4 + j;                 // logical order: idx = b*8 + r
        int x = 0;
        if (idx < NCTR) x = ghist[(idx & 7) * BKT + (idx >> 3)];
        v[j] = x; sum += x;
    }
    c[t] = sum;
    __syncthreads();
    for (int off = 1; off < 1024; off <<= 1) {
        int u = (t >= off) ? c[t - off] : 0;
        __syncthreads();
        c[t] += u;
        __syncthreads();
    }
    int run = (t == 0) ? 0 : c[t - 1];
    #pragma unroll
    for (int j = 0; j < 4; ++j) {
        int idx = t * 4 + j;
        if (idx < NCTR) {
            bbase[idx] = run;
            bcur[(idx & 7) * BKT + (idx >> 3)] = run;
        }
        run += v[j];
    }
    if (t == 1023) bbase[NCTR] = run;
}

// ---------------- pass 3: multisplit scatter ----------------
__global__ __launch_bounds__(256) void p2_kernel(const int* __restrict__ src, const int* __restrict__ dst,
                                                 int* __restrict__ bcur, unsigned int* __restrict__ packed) {
    __shared__ int h[BKT], gb[BKT], lc[BKT];
    int t = threadIdx.x;
    for (int i = t; i < BKT; i += 256) { h[i] = 0; lc[i] = 0; }
    __syncthreads();
    size_t base = (size_t)blockIdx.x * T2;
    for (int kk = 0; kk < 32; ++kk) {
        size_t e = base + (size_t)kk * 1024 + t * 4;
        if (e + 4 <= NE) {
            int4 d = *(const int4*)(dst + e);
            atomicAdd(&h[d.x >> 9], 1);
            atomicAdd(&h[d.y >> 9], 1);
            atomicAdd(&h[d.z >> 9], 1);
            atomicAdd(&h[d.w >> 9], 1);
        } else {
            for (int j = 0; j < 4; ++j)
                if (e + j < NE) atomicAdd(&h[dst[e + j] >> 9], 1);
        }
    }
    __syncthreads();
    int r = blockIdx.x & 7;
    for (int i = t; i < BKT; i += 256)
        gb[i] = h[i] ? atomicAdd(&bcur[r * BKT + i], h[i]) : 0;
    __syncthreads();
    for (int kk = 0; kk < 32; ++kk) {
        size_t e = base + (size_t)kk * 1024 + t * 4;
        if (e + 4 <= NE) {
            int4 d = *(const int4*)(dst + e);
            int4 s = *(const int4*)(src + e);
            int b, p;
            b = d.x >> 9; p = gb[b] + atomicAdd(&lc[b], 1); packed[p] = ((unsigned)s.x << 9) | (unsigned)(d.x & 511);
            b = d.y >> 9; p = gb[b] + atomicAdd(&lc[b], 1); packed[p] = ((unsigned)s.y << 9) | (unsigned)(d.y & 511);
            b = d.z >> 9; p = gb[b] + atomicAdd(&lc[b], 1); packed[p] = ((unsigned)s.z << 9) | (unsigned)(d.z & 511);
            b = d.w >> 9; p = gb[b] + atomicAdd(&lc[b], 1); packed[p] = ((unsigned)s.w << 9) | (unsigned)(d.w & 511);
        } else {
            for (int j = 0; j < 4; ++j) {
                if (e + j < NE) {
                    int dd = dst[e + j], ssv = src[e + j];
                    int b = dd >> 9;
                    int p = gb[b] + atomicAdd(&lc[b], 1);
                    packed[p] = ((unsigned)ssv << 9) | (unsigned)(dd & 511);
                }
            }
        }
    }
}

// ---------------- pass 4: per-bucket CSR finalize, segments ordered by (dst_low, src_slice) ----------------
__global__ __launch_bounds__(256) void p3_kernel(const unsigned int* __restrict__ packed, const int* __restrict__ bbase,
                                                 int* __restrict__ col, int* __restrict__ rowstart,
                                                 float* __restrict__ dinv) {
    __shared__ int lcnt[BNODE * NSLC], lexc[BNODE * NSLC], lcur[BNODE * NSLC];
    __shared__ int tmp[256];
    int t = threadIdx.x;
    int b = blockIdx.x;
    for (int i = t; i < BNODE * NSLC; i += 256) { lcnt[i] = 0; lcur[i] = 0; }
    __syncthreads();
    int beg = bbase[b * 8], end = bbase[(b + 1) * 8];
    for (int i = beg + t; i < end; i += 256) {
        unsigned p = packed[i];
        int k = (int)(p & 511) * NSLC + (int)(p >> 9) / SLCW;
        atomicAdd(&lcnt[k], 1);
    }
    __syncthreads();
    int myv[8];
    int ssum = 0;
    #pragma unroll
    for (int j = 0; j < 8; ++j) { myv[j] = lcnt[t * 8 + j]; ssum += myv[j]; }
    tmp[t] = ssum;
    __syncthreads();
    for (int off = 1; off < 256; off <<= 1) {
        int u = (t >= off) ? tmp[t - off] : 0;
        __syncthreads();
        tmp[t] += u;
        __syncthreads();
    }
    int run = (t == 0) ? 0 : tmp[t - 1];
    #pragma unroll
    for (int j = 0; j < 8; ++j) { lexc[t * 8 + j] = run; run += myv[j]; }
    __syncthreads();
    for (int i = beg + t; i < end; i += 256) {
        unsigned p = packed[i];
        int sv = (int)(p >> 9);
        int k = (int)(p & 511) * NSLC + sv / SLCW;
        int pos = lexc[k] + atomicAdd(&lcur[k], 1);
        col[beg + pos] = sv;
    }
    __syncthreads();
    int n0 = b * BNODE;
    for (int i = t; i < BNODE; i += 256) {
        int n = n0 + i;
        if (n < NN) {
            int st = lexc[i * NSLC];
            int en = (i == BNODE - 1) ? (end - beg) : lexc[(i + 1) * NSLC];
            rowstart[n] = beg + en;                       // exclusive row end
            dinv[n] = rsqrtf(1.0f + (float)(en - st));
        }
    }
}

// ---------------- layer0 linear: (yA,yB) bf16 = (x @ W0) * dinv ----------------
__global__ __launch_bounds__(256) void lin0_kernel(const float* __restrict__ x, const float* __restrict__ W,
                                                   const float* __restrict__ dinv,
                                                   ushort_t* __restrict__ yA, ushort_t* __restrict__ yB) {
    __shared__ float sW[FIN * DIM];
    __shared__ float sX[64 * 65];
    __shared__ ushort_t sO[64 * 32];
    int tid = threadIdx.x;
    for (int i = tid; i < FIN * DIM; i += 256) sW[i] = W[i];
    int n0 = blockIdx.x * 64;
    #pragma unroll
    for (int k = 0; k < 16; ++k) {
        int idx = tid + k * 256;
        int row = idx >> 6, colf = idx & 63;
        sX[row * 65 + colf] = x[(size_t)(n0 + row) * FIN + colf];
    }
    __syncthreads();
    int nl = tid & 63, wq = tid >> 6;
    float acc[5] = {0.f, 0.f, 0.f, 0.f, 0.f};
    for (int f = 0; f < FIN; ++f) {
        float xv = sX[nl * 65 + f];
        #pragma unroll
        for (int k = 0; k < 5; ++k) acc[k] += xv * sW[f * DIM + wq + 4 * k];
    }
    float dv = dinv[n0 + nl];
    #pragma unroll
    for (int k = 0; k < 5; ++k) sO[nl * 32 + wq + 4 * k] = f2bf(acc[k] * dv);
    __syncthreads();
    if (tid < 128) {                                       // yA: 64 rows x 2 uint4
        int row = tid >> 1, part = tid & 1;
        ((uint4*)(yA + (size_t)(n0 + row) * 16))[part] = ((const uint4*)(sO + row * 32))[part];
    } else if (tid < 192) {                                // yB: 64 rows x 1 uint2
        int row = tid - 128;
        *(uint2*)(yB + (size_t)(n0 + row) * 4) = *(const uint2*)(sO + row * 32 + 16);
    }
}

// ---------------- CSR gather: 2 lanes/node, asm 4-row MLP, split L2-resident rows ----------------
__global__ __launch_bounds__(256) void gather_kernel(const ushort_t* __restrict__ yA, const ushort_t* __restrict__ yB,
                                                     const int* __restrict__ col, const int* __restrict__ rowstart,
                                                     const float* __restrict__ dinv, const float* __restrict__ bia,
                                                     float* __restrict__ agg, float* __restrict__ stats) {
    __shared__ float ls[2 * DIM];
    int tid = threadIdx.x;
    if (tid < 2 * DIM) ls[tid] = 0.f;
    __syncthreads();
    int n = blockIdx.x * 128 + (tid >> 1);
    int h = tid & 1;
    float acc[DIM];
    if (n < NN) {
        #pragma unroll
        for (int j = 0; j < DIM; ++j) acc[j] = 0.f;
        if (h == 0) {                                       // self-loop
            uint4 ra, rb; uint2 rc;
            row_load_plain(yA, yB, n, ra, rb, rc);
            acc10(ra, rb, rc, acc);
        }
        int beg = (n == 0) ? 0 : rowstart[n - 1];
        int end = rowstart[n];
        int e = beg + h;
        int cnt = (end - e + 1) >> 1;
        if (end <= e) cnt = 0;
        while (cnt >= 4) {                                  // 12 loads truly outstanding
            int s0 = __builtin_nontemporal_load(&col[e]);
            int s1 = __builtin_nontemporal_load(&col[e + 2]);
            int s2 = __builtin_nontemporal_load(&col[e + 4]);
            int s3 = __builtin_nontemporal_load(&col[e + 6]);
            uint4 a0, b0, a1, b1, a2, b2, a3, b3;
            uint2 c0, c1, c2, c3;
            row_load_asm(yA, yB, s0, a0, b0, c0);
            row_load_asm(yA, yB, s1, a1, b1, c1);
            row_load_asm(yA, yB, s2, a2, b2, c2);
            row_load_asm(yA, yB, s3, a3, b3, c3);
            asm volatile("s_waitcnt vmcnt(0)" ::: "memory");
            __builtin_amdgcn_sched_barrier(0);
            acc10(a0, b0, c0, acc);
            acc10(a1, b1, c1, acc);
            acc10(a2, b2, c2, acc);
            acc10(a3, b3, c3, acc);
            e += 8; cnt -= 4;
        }
        if (cnt >= 2) {
            int s0 = __builtin_nontemporal_load(&col[e]);
            int s1 = __builtin_nontemporal_load(&col[e + 2]);
            uint4 a0, b0, a1, b1;
            uint2 c0, c1;
            row_load_asm(yA, yB, s0, a0, b0, c0);
            row_load_asm(yA, yB, s1, a1, b1, c1);
            asm volatile("s_waitcnt vmcnt(0)" ::: "memory");
            __builtin_amdgcn_sched_barrier(0);
            acc10(a0, b0, c0, acc);
            acc10(a1, b1, c1, acc);
            e += 4; cnt -= 2;
        }
        if (cnt > 0) {
            int s0 = __builtin_nontemporal_load(&col[e]);
            uint4 ra, rb; uint2 rc;
            row_load_plain(yA, yB, s0, ra, rb, rc);
            acc10(ra, rb, rc, acc);
        }
        float di = dinv[n];
        #pragma unroll
        for (int j = 0; j < DIM; ++j) {
            acc[j] += __shfl_xor(acc[j], 1, 64);
            acc[j] = acc[j] * di + bia[j];
        }
        float* ar = agg + (size_t)n * DIM;
        if (h == 0) {
            nt_store4(ar,     acc[0], acc[1], acc[2], acc[3]);
            nt_store4(ar + 4, acc[4], acc[5], acc[6], acc[7]);
            nt_store4(ar + 8, acc[8], acc[9], acc[10], acc[11]);
        } else {
            nt_store4(ar + 12, acc[12], acc[13], acc[14], acc[15]);
            nt_store4(ar + 16, acc[16], acc[17], acc[18], acc[19]);
        }
        int pr = tid >> 1;
        #pragma unroll
        for (int jo = 0; jo < 10; ++jo) {
            int j = ((jo + pr) % 10) + 10 * h;
            atomicAdd(&ls[j], acc[j]);
            atomicAdd(&ls[DIM + j], acc[j] * acc[j]);
        }
    }
    __syncthreads();
    if (tid < 2 * DIM) atomicAdd(&stats[tid], ls[tid]);
}

// ---------------- next linear (BN folded): (yA,yB) = (relu(bn(agg)) @ W) * dinv ----------------
__global__ __launch_bounds__(256) void lin_next_kernel(const float* __restrict__ a, const float* __restrict__ stats,
                                                       const float* __restrict__ g, const float* __restrict__ beta,
                                                       const float* __restrict__ W, const float* __restrict__ dinv,
                                                       ushort_t* __restrict__ yA, ushort_t* __restrict__ yB) {
    __shared__ float sW[DIM * DIM];
    __shared__ float sH[64 * 21];
    __shared__ float sS[2 * DIM];
    __shared__ ushort_t sO[64 * 32];
    int tid = threadIdx.x;
    for (int i = tid; i < DIM * DIM; i += 256) sW[i] = W[i];
    if (tid < DIM) {
        float mean = stats[tid] * (1.0f / NN);
        float var = stats[DIM + tid] * (1.0f / NN) - mean * mean;
        float sc = g[tid] * rsqrtf(var + BN_EPS);
        sS[tid] = sc;
        sS[DIM + tid] = beta[tid] - mean * sc;
    }
    __syncthreads();
    int n0 = blockIdx.x * 64;
    #pragma unroll
    for (int k = 0; k < 5; ++k) {
        int idx = tid + k * 256;
        int row = idx / DIM, colf = idx - row * DIM;
        float v = a[(size_t)(n0 + row) * DIM + colf];
        sH[row * 21 + colf] = fmaxf(v * sS[colf] + sS[DIM + colf], 0.0f);
    }
    __syncthreads();
    int nl = tid & 63, wq = tid >> 6;
    float acc[5] = {0.f, 0.f, 0.f, 0.f, 0.f};
    for (int f = 0; f < DIM; ++f) {
        float h = sH[nl * 21 + f];
        #pragma unroll
        for (int k = 0; k < 5; ++k) acc[k] += h * sW[f * DIM + wq + 4 * k];
    }
    float dv = dinv[n0 + nl];
    #pragma unroll
    for (int k = 0; k < 5; ++k) sO[nl * 32 + wq + 4 * k] = f2bf(acc[k] * dv);
    __syncthreads();
    if (tid < 128) {
        int row = tid >> 1, part = tid & 1;
        ((uint4*)(yA + (size_t)(n0 + row) * 16))[part] = ((const uint4*)(sO + row * 32))[part];
    } else if (tid < 192) {
        int row = tid - 128;
        *(uint2*)(yB + (size_t)(n0 + row) * 4) = *(const uint2*)(sO + row * 32 + 16);
    }
}

// ---------------- final (BN folded): relu(bn) -> emb + segment_max ----------------
__global__ __launch_bounds__(256) void final_kernel(const float* __restrict__ a, const float* __restrict__ stats,
                                                    const float* __restrict__ g, const float* __restrict__ beta,
                                                    const int* __restrict__ batch, float* __restrict__ emb,
                                                    unsigned int* __restrict__ ge) {
    __shared__ unsigned int lmax[8 * DIM];
    __shared__ float sS[2 * DIM];
    __shared__ int sg[2];
    int tid = threadIdx.x;
    if (tid < DIM) {
        float mean = stats[tid] * (1.0f / NN);
        float var = stats[DIM + tid] * (1.0f / NN) - mean * mean;
        float sc = g[tid] * rsqrtf(var + BN_EPS);
        sS[tid] = sc;
        sS[DIM + tid] = beta[tid] - mean * sc;
    }
    int n0 = blockIdx.x * 256;
    if (tid == 0) {
        int nlast = min(n0 + 255, NN - 1);
        sg[0] = batch[n0];
        sg[1] = batch[nlast] - batch[n0] + 1;
    }
    for (int i = tid; i < 8 * DIM; i += 256) lmax[i] = 0u;
    __syncthreads();
    int gmin = sg[0], gspan = sg[1];
    bool uselds = (gspan <= 8);
    int n = n0 + tid;
    if (n < NN) {
        int g2 = batch[n];
        float vals[DIM];
        const float4* ar = (const float4*)(a + (size_t)n * DIM);
        float4* er = (float4*)(emb + (size_t)n * DIM);
        #pragma unroll
        for (int c = 0; c < 5; ++c) {
            float4 v = ar[c];
            float r0 = fmaxf(v.x * sS[4*c+0] + sS[DIM + 4*c+0], 0.0f);
            float r1 = fmaxf(v.y * sS[4*c+1] + sS[DIM + 4*c+1], 0.0f);
            float r2 = fmaxf(v.z * sS[4*c+2] + sS[DIM + 4*c+2], 0.0f);
            float r3 = fmaxf(v.w * sS[4*c+3] + sS[DIM + 4*c+3], 0.0f);
            er[c] = make_float4(r0, r1, r2, r3);
            vals[4*c+0] = r0; vals[4*c+1] = r1; vals[4*c+2] = r2; vals[4*c+3] = r3;
        }
        if (uselds) {
            int base = (g2 - gmin) * DIM;
            #pragma unroll
            for (int jo = 0; jo < DIM; ++jo) {
                int j = (jo + tid) % DIM;
                atomicMax(&lmax[base + j], __float_as_uint(vals[j]));
            }
        } else {
            #pragma unroll
            for (int jo = 0; jo < DIM; ++jo) {
                int j = (jo + tid) % DIM;
                atomicMax(&ge[g2 * DIM + j], __float_as_uint(vals[j]));
            }
        }
    }
    __syncthreads();
    if (uselds) {
        for (int i = tid; i < gspan * DIM; i += 256) {
            unsigned int v = lmax[i];
            if (v) atomicMax(&ge[gmin * DIM + i], v);
        }
    }
}

// ---------------- fc head ----------------
__global__ __launch_bounds__(256) void fc_kernel(const float* __restrict__ ge, const float* __restrict__ fcW,
                                                 const float* __restrict__ fcb, float* __restrict__ out) {
    int gid = blockIdx.x * 256 + threadIdx.x;
    if (gid >= NGR * NCL) return;
    int g = gid >> 1, c = gid & 1;
    float acc = fcb[c];
    #pragma unroll
    for (int d = 0; d < DIM; ++d) acc += ge[g * DIM + d] * fcW[d * NCL + c];
    out[gid] = acc;
}

extern "C" void kernel_launch(void* const* d_in, const int* in_sizes, int n_in,
                              void* d_out, int out_size, void* d_ws, size_t ws_size,
                              hipStream_t stream) {
    const float* x     = (const float*)d_in[0];
    const int*   ei    = (const int*)d_in[1];
    const int*   src   = ei;
    const int*   dst   = ei + NE;
    const int*   batch = (const int*)d_in[2];
    const float* W0 = (const float*)d_in[3];  const float* b0 = (const float*)d_in[4];
    const float* g0 = (const float*)d_in[5];  const float* be0 = (const float*)d_in[6];
    const float* W1 = (const float*)d_in[7];  const float* b1 = (const float*)d_in[8];
    const float* g1 = (const float*)d_in[9];  const float* be1 = (const float*)d_in[10];
    const float* W2 = (const float*)d_in[11]; const float* b2 = (const float*)d_in[12];
    const float* g2 = (const float*)d_in[13]; const float* be2 = (const float*)d_in[14];
    const float* fcW = (const float*)d_in[15]; const float* fcb = (const float*)d_in[16];

    float* ws = (float*)d_ws;
    float* dinv     = ws;                               // NN
    int*   rowstart = (int*)(ws + NN);                  // NN (exclusive row ends)
    float* stats    = ws + 2 * NN;                      // 192
    int*   ghist    = (int*)(stats + 192);              // NCTR
    int*   bbase    = ghist + NCTR;                     // NCTR+1
    int*   bcur     = bbase + NCTR + 1;                 // NCTR
    float* agg      = ws + 409700;                      // NN*DIM fp32; aliases packed[]
    unsigned int* packed = (unsigned int*)agg;          // NE u32 == NN*DIM
    ushort_t* yA    = (ushort_t*)(ws + 4409712);        // NN x 32B (feats 0..15)
    ushort_t* yB    = (ushort_t*)(ws + 6009712);        // NN x 8B  (feats 16..19)
    int*   col      = (int*)(ws + 6409712);             // NE ints

    float* emb    = (float*)d_out;                      // NN*DIM
    float* ge     = emb + (size_t)NN * DIM;             // NGR*DIM
    float* logits = ge + NGR * DIM;                     // NGR*NCL

    const int N_BLKS = (NN + 255) / 256;                // 782
    const int L_BLKS = NN / 64;                         // 3125 (linears)
    const int G_BLKS = (NN + 127) / 128;                // 1563 (gather)

    hipMemsetAsync(ghist, 0, NCTR * sizeof(int), stream);
    hipMemsetAsync(stats, 0, 192 * sizeof(float), stream);
    hipMemsetAsync(ge, 0, NGR * DIM * sizeof(float), stream);

    // ---- CSR build: two-level multisplit, (dst_low, src_slice)-sorted segments ----
    hist_kernel<<<NT2, 256, 0, stream>>>(dst, ghist);
    scan_small_kernel<<<1, 1024, 0, stream>>>(ghist, bbase, bcur);
    p2_kernel<<<NT2, 256, 0, stream>>>(src, dst, bcur, packed);
    p3_kernel<<<BKT, 256, 0, stream>>>(packed, bbase, col, rowstart, dinv);

    lin0_kernel<<<L_BLKS, 256, 0, stream>>>(x, W0, dinv, yA, yB);   // packed dead after p3

    gather_kernel<<<G_BLKS, 256, 0, stream>>>(yA, yB, col, rowstart, dinv, b0, agg, stats);
    lin_next_kernel<<<L_BLKS, 256, 0, stream>>>(agg, stats, g0, be0, W1, dinv, yA, yB);

    gather_kernel<<<G_BLKS, 256, 0, stream>>>(yA, yB, col, rowstart, dinv, b1, agg, stats + 64);
    lin_next_kernel<<<L_BLKS, 256, 0, stream>>>(agg, stats + 64, g1, be1, W2, dinv, yA, yB);

    gather_kernel<<<G_BLKS, 256, 0, stream>>>(yA, yB, col, rowstart, dinv, b2, agg, stats + 128);

    final_kernel<<<N_BLKS, 256, 0, stream>>>(agg, stats + 128, g2, be2, batch, emb, (unsigned int*)ge);
    fc_kernel<<<(NGR * NCL + 255) / 256, 256, 0, stream>>>(ge, fcW, fcb, logits);
}

// Round 19
// 421.800 us; speedup vs baseline: 1.1134x; 1.1134x over previous
//
#include <hip/hip_runtime.h>

#define NN 200000
#define NE 4000000
#define FIN 64
#define DIM 20
#define NGR 512
#define NCL 2
#define BN_EPS 1e-5f

#define BKT 391                 // buckets of 512 nodes (dst>>9)
#define BNODE 512
#define NCTR (8 * BKT)
#define T2 32768
#define NT2 ((NE + T2 - 1) / T2)   // 123
#define NSLC 4
#define SLCW 50000              // src-slice width

typedef unsigned short ushort_t;

__device__ __forceinline__ ushort_t f2bf(float f) {   // RNE bf16
    unsigned u = __float_as_uint(f);
    unsigned r = (u + 0x7fffu + ((u >> 16) & 1u)) >> 16;
    return (ushort_t)r;
}

struct Row { uint4 a, b; uint2 c; };

__device__ __forceinline__ Row row_load(const ushort_t* __restrict__ yb, int s) {
    const uint4* rp = (const uint4*)(yb + (size_t)s * 32);
    Row r;
    r.a = rp[0];
    r.b = rp[1];
    r.c = ((const uint2*)rp)[4];
    return r;
}

__device__ __forceinline__ void row_acc(const Row& r, float* acc) {
    unsigned u[10] = {r.a.x, r.a.y, r.a.z, r.a.w, r.b.x, r.b.y, r.b.z, r.b.w, r.c.x, r.c.y};
    #pragma unroll
    for (int i = 0; i < 10; ++i) {
        acc[2 * i]     += __uint_as_float(u[i] << 16);
        acc[2 * i + 1] += __uint_as_float(u[i] & 0xffff0000u);
    }
}

// asm row load: 3 opaque loads -> results pinned in VGPRs until the waitcnt
__device__ __forceinline__ void row_load_asm(const ushort_t* yb, int s, uint4& ra, uint4& rb, uint2& rc) {
    unsigned long long ap = (unsigned long long)(yb + (size_t)s * 32);
    asm volatile("global_load_dwordx4 %0, %1, off"           : "=v"(ra) : "v"(ap));
    asm volatile("global_load_dwordx4 %0, %1, off offset:16" : "=v"(rb) : "v"(ap));
    asm volatile("global_load_dwordx2 %0, %1, off offset:32" : "=v"(rc) : "v"(ap));
}

__device__ __forceinline__ void acc10(const uint4& a, const uint4& b, const uint2& c, float* acc) {
    unsigned u[10] = {a.x, a.y, a.z, a.w, b.x, b.y, b.z, b.w, c.x, c.y};
    #pragma unroll
    for (int i = 0; i < 10; ++i) {
        acc[2 * i]     += __uint_as_float(u[i] << 16);
        acc[2 * i + 1] += __uint_as_float(u[i] & 0xffff0000u);
    }
}

// ---------------- pass 1: per-(xcd,bucket) edge histogram ----------------
__global__ __launch_bounds__(256) void hist_kernel(const int* __restrict__ dst, int* __restrict__ ghist) {
    __shared__ int h[BKT];
    int t = threadIdx.x;
    for (int i = t; i < BKT; i += 256) h[i] = 0;
    __syncthreads();
    size_t base = (size_t)blockIdx.x * T2;
    for (int kk = 0; kk < 32; ++kk) {
        size_t e = base + (size_t)kk * 1024 + t * 4;
        if (e + 4 <= NE) {
            int4 d = *(const int4*)(dst + e);
            atomicAdd(&h[d.x >> 9], 1);
            atomicAdd(&h[d.y >> 9], 1);
            atomicAdd(&h[d.z >> 9], 1);
            atomicAdd(&h[d.w >> 9], 1);
        } else {
            for (int j = 0; j < 4; ++j)
                if (e + j < NE) atomicAdd(&h[dst[e + j] >> 9], 1);
        }
    }
    __syncthreads();
    int r = blockIdx.x & 7;
    for (int i = t; i < BKT; i += 256)
        if (h[i]) atomicAdd(&ghist[r * BKT + i], h[i]);
}

// ---------------- pass 2: scan 3128 counters ----------------
__global__ __launch_bounds__(1024) void scan_small_kernel(const int* __restrict__ ghist,
                                                          int* __restrict__ bbase, int* __restrict__ bcur) {
    __shared__ int c[1024];
    int t = threadIdx.x;
    int v[4];
    int sum = 0;
    #pragma unroll
    for (int j = 0; j < 4; ++j) {
        int idx = t * 4 + j;                 // logical order: idx = b*8 + r
        int x = 0;
        if (idx < NCTR) x = ghist[(idx & 7) * BKT + (idx >> 3)];
        v[j] = x; sum += x;
    }
    c[t] = sum;
    __syncthreads();
    for (int off = 1; off < 1024; off <<= 1) {
        int u = (t >= off) ? c[t - off] : 0;
        __syncthreads();
        c[t] += u;
        __syncthreads();
    }
    int run = (t == 0) ? 0 : c[t - 1];
    #pragma unroll
    for (int j = 0; j < 4; ++j) {
        int idx = t * 4 + j;
        if (idx < NCTR) {
            bbase[idx] = run;
            bcur[(idx & 7) * BKT + (idx >> 3)] = run;
        }
        run += v[j];
    }
    if (t == 1023) bbase[NCTR] = run;
}

// ---------------- pass 3: multisplit scatter ----------------
__global__ __launch_bounds__(256) void p2_kernel(const int* __restrict__ src, const int* __restrict__ dst,
                                                 int* __restrict__ bcur, unsigned int* __restrict__ packed) {
    __shared__ int h[BKT], gb[BKT], lc[BKT];
    int t = threadIdx.x;
    for (int i = t; i < BKT; i += 256) { h[i] = 0; lc[i] = 0; }
    __syncthreads();
    size_t base = (size_t)blockIdx.x * T2;
    for (int kk = 0; kk < 32; ++kk) {
        size_t e = base + (size_t)kk * 1024 + t * 4;
        if (e + 4 <= NE) {
            int4 d = *(const int4*)(dst + e);
            atomicAdd(&h[d.x >> 9], 1);
            atomicAdd(&h[d.y >> 9], 1);
            atomicAdd(&h[d.z >> 9], 1);
            atomicAdd(&h[d.w >> 9], 1);
        } else {
            for (int j = 0; j < 4; ++j)
                if (e + j < NE) atomicAdd(&h[dst[e + j] >> 9], 1);
        }
    }
    __syncthreads();
    int r = blockIdx.x & 7;
    for (int i = t; i < BKT; i += 256)
        gb[i] = h[i] ? atomicAdd(&bcur[r * BKT + i], h[i]) : 0;
    __syncthreads();
    for (int kk = 0; kk < 32; ++kk) {
        size_t e = base + (size_t)kk * 1024 + t * 4;
        if (e + 4 <= NE) {
            int4 d = *(const int4*)(dst + e);
            int4 s = *(const int4*)(src + e);
            int b, p;
            b = d.x >> 9; p = gb[b] + atomicAdd(&lc[b], 1); packed[p] = ((unsigned)s.x << 9) | (unsigned)(d.x & 511);
            b = d.y >> 9; p = gb[b] + atomicAdd(&lc[b], 1); packed[p] = ((unsigned)s.y << 9) | (unsigned)(d.y & 511);
            b = d.z >> 9; p = gb[b] + atomicAdd(&lc[b], 1); packed[p] = ((unsigned)s.z << 9) | (unsigned)(d.z & 511);
            b = d.w >> 9; p = gb[b] + atomicAdd(&lc[b], 1); packed[p] = ((unsigned)s.w << 9) | (unsigned)(d.w & 511);
        } else {
            for (int j = 0; j < 4; ++j) {
                if (e + j < NE) {
                    int dd = dst[e + j], ssv = src[e + j];
                    int b = dd >> 9;
                    int p = gb[b] + atomicAdd(&lc[b], 1);
                    packed[p] = ((unsigned)ssv << 9) | (unsigned)(dd & 511);
                }
            }
        }
    }
}

// ---------------- pass 4: per-bucket CSR finalize, segments ordered by (dst_low, src_slice) ----------------
__global__ __launch_bounds__(256) void p3_kernel(const unsigned int* __restrict__ packed, const int* __restrict__ bbase,
                                                 int* __restrict__ col, int* __restrict__ rowstart,
                                                 float* __restrict__ dinv) {
    __shared__ int lcnt[BNODE * NSLC], lexc[BNODE * NSLC], lcur[BNODE * NSLC];
    __shared__ int tmp[256];
    int t = threadIdx.x;
    int b = blockIdx.x;
    for (int i = t; i < BNODE * NSLC; i += 256) { lcnt[i] = 0; lcur[i] = 0; }
    __syncthreads();
    int beg = bbase[b * 8], end = bbase[(b + 1) * 8];
    for (int i = beg + t; i < end; i += 256) {
        unsigned p = packed[i];
        int k = (int)(p & 511) * NSLC + (int)(p >> 9) / SLCW;
        atomicAdd(&lcnt[k], 1);
    }
    __syncthreads();
    int myv[8];
    int ssum = 0;
    #pragma unroll
    for (int j = 0; j < 8; ++j) { myv[j] = lcnt[t * 8 + j]; ssum += myv[j]; }
    tmp[t] = ssum;
    __syncthreads();
    for (int off = 1; off < 256; off <<= 1) {
        int u = (t >= off) ? tmp[t - off] : 0;
        __syncthreads();
        tmp[t] += u;
        __syncthreads();
    }
    int run = (t == 0) ? 0 : tmp[t - 1];
    #pragma unroll
    for (int j = 0; j < 8; ++j) { lexc[t * 8 + j] = run; run += myv[j]; }
    __syncthreads();
    for (int i = beg + t; i < end; i += 256) {
        unsigned p = packed[i];
        int sv = (int)(p >> 9);
        int k = (int)(p & 511) * NSLC + sv / SLCW;
        int pos = lexc[k] + atomicAdd(&lcur[k], 1);
        col[beg + pos] = sv;
    }
    __syncthreads();
    int n0 = b * BNODE;
    for (int i = t; i < BNODE; i += 256) {
        int n = n0 + i;
        if (n < NN) {
            int st = lexc[i * NSLC];
            int en = (i == BNODE - 1) ? (end - beg) : lexc[(i + 1) * NSLC];
            rowstart[n] = beg + en;                       // exclusive row end
            dinv[n] = rsqrtf(1.0f + (float)(en - st));
        }
    }
}

// ---------------- layer0 linear: y_bf16 = (x @ W0) * dinv ----------------
__global__ __launch_bounds__(256) void lin0_kernel(const float* __restrict__ x, const float* __restrict__ W,
                                                   const float* __restrict__ dinv, ushort_t* __restrict__ yb) {
    __shared__ float sW[FIN * DIM];
    __shared__ float sX[64 * 65];
    __shared__ ushort_t sO[64 * 32];
    int tid = threadIdx.x;
    for (int i = tid; i < FIN * DIM; i += 256) sW[i] = W[i];
    int n0 = blockIdx.x * 64;
    #pragma unroll
    for (int k = 0; k < 16; ++k) {
        int idx = tid + k * 256;
        int row = idx >> 6, colf = idx & 63;
        sX[row * 65 + colf] = x[(size_t)(n0 + row) * FIN + colf];
    }
    __syncthreads();
    int nl = tid & 63, wq = tid >> 6;
    float acc[5] = {0.f, 0.f, 0.f, 0.f, 0.f};
    for (int f = 0; f < FIN; ++f) {
        float xv = sX[nl * 65 + f];
        #pragma unroll
        for (int k = 0; k < 5; ++k) acc[k] += xv * sW[f * DIM + wq + 4 * k];
    }
    float dv = dinv[n0 + nl];
    #pragma unroll
    for (int k = 0; k < 5; ++k) sO[nl * 32 + wq + 4 * k] = f2bf(acc[k] * dv);
    __syncthreads();
    if (tid < 192) {                                   // 64 rows x 3 uint4 (bytes 0..47)
        int row = tid / 3, part = tid - row * 3;
        ((uint4*)(yb + (size_t)(n0 + row) * 32))[part] = ((const uint4*)(sO + row * 32))[part];
    }
}

// ---------------- CSR gather: 2 lanes/node, forced 4-row MLP via inline-asm loads ----------------
__global__ __launch_bounds__(256) void gather_kernel(const ushort_t* __restrict__ yb, const int* __restrict__ col,
                                                     const int* __restrict__ rowstart, const float* __restrict__ dinv,
                                                     const float* __restrict__ bia, float* __restrict__ agg,
                                                     float* __restrict__ stats) {
    __shared__ float ls[2 * DIM];
    int tid = threadIdx.x;
    if (tid < 2 * DIM) ls[tid] = 0.f;
    __syncthreads();
    int n = blockIdx.x * 128 + (tid >> 1);
    int h = tid & 1;
    float acc[DIM];
    if (n < NN) {
        #pragma unroll
        for (int j = 0; j < DIM; ++j) acc[j] = 0.f;
        if (h == 0) row_acc(row_load(yb, n), acc);               // self-loop
        int beg = (n == 0) ? 0 : rowstart[n - 1];
        int end = rowstart[n];
        int e = beg + h;
        int cnt = (end - e + 1) >> 1;
        if (end <= e) cnt = 0;
        while (cnt >= 4) {                                       // 12 loads truly outstanding
            int s0 = col[e], s1 = col[e + 2], s2 = col[e + 4], s3 = col[e + 6];
            uint4 a0, b0, a1, b1, a2, b2, a3, b3;
            uint2 c0, c1, c2, c3;
            row_load_asm(yb, s0, a0, b0, c0);
            row_load_asm(yb, s1, a1, b1, c1);
            row_load_asm(yb, s2, a2, b2, c2);
            row_load_asm(yb, s3, a3, b3, c3);
            asm volatile("s_waitcnt vmcnt(0)" ::: "memory");
            __builtin_amdgcn_sched_barrier(0);
            acc10(a0, b0, c0, acc);
            acc10(a1, b1, c1, acc);
            acc10(a2, b2, c2, acc);
            acc10(a3, b3, c3, acc);
            e += 8; cnt -= 4;
        }
        if (cnt >= 2) {
            int s0 = col[e], s1 = col[e + 2];
            uint4 a0, b0, a1, b1;
            uint2 c0, c1;
            row_load_asm(yb, s0, a0, b0, c0);
            row_load_asm(yb, s1, a1, b1, c1);
            asm volatile("s_waitcnt vmcnt(0)" ::: "memory");
            __builtin_amdgcn_sched_barrier(0);
            acc10(a0, b0, c0, acc);
            acc10(a1, b1, c1, acc);
            e += 4; cnt -= 2;
        }
        if (cnt > 0) row_acc(row_load(yb, col[e]), acc);
        float di = dinv[n];
        #pragma unroll
        for (int j = 0; j < DIM; ++j) {
            acc[j] += __shfl_xor(acc[j], 1, 64);
            acc[j] = acc[j] * di + bia[j];
        }
        float* ar = agg + (size_t)n * DIM;
        if (h == 0) {
            *(float4*)(ar)     = make_float4(acc[0], acc[1], acc[2], acc[3]);
            *(float4*)(ar + 4) = make_float4(acc[4], acc[5], acc[6], acc[7]);
            *(float4*)(ar + 8) = make_float4(acc[8], acc[9], acc[10], acc[11]);
        } else {
            *(float4*)(ar + 12) = make_float4(acc[12], acc[13], acc[14], acc[15]);
            *(float4*)(ar + 16) = make_float4(acc[16], acc[17], acc[18], acc[19]);
        }
        int pr = tid >> 1;
        #pragma unroll
        for (int jo = 0; jo < 10; ++jo) {
            int j = ((jo + pr) % 10) + 10 * h;
            atomicAdd(&ls[j], acc[j]);
            atomicAdd(&ls[DIM + j], acc[j] * acc[j]);
        }
    }
    __syncthreads();
    if (tid < 2 * DIM) atomicAdd(&stats[tid], ls[tid]);
}

// ---------------- next linear (BN folded): y_bf16 = (relu(bn(agg)) @ W) * dinv ----------------
__global__ __launch_bounds__(256) void lin_next_kernel(const float* __restrict__ a, const float* __restrict__ stats,
                                                       const float* __restrict__ g, const float* __restrict__ beta,
                                                       const float* __restrict__ W, const float* __restrict__ dinv,
                                                       ushort_t* __restrict__ yb) {
    __shared__ float sW[DIM * DIM];
    __shared__ float sH[64 * 21];
    __shared__ float sS[2 * DIM];
    __shared__ ushort_t sO[64 * 32];
    int tid = threadIdx.x;
    for (int i = tid; i < DIM * DIM; i += 256) sW[i] = W[i];
    if (tid < DIM) {
        float mean = stats[tid] * (1.0f / NN);
        float var = stats[DIM + tid] * (1.0f / NN) - mean * mean;
        float sc = g[tid] * rsqrtf(var + BN_EPS);
        sS[tid] = sc;
        sS[DIM + tid] = beta[tid] - mean * sc;
    }
    __syncthreads();
    int n0 = blockIdx.x * 64;
    #pragma unroll
    for (int k = 0; k < 5; ++k) {
        int idx = tid + k * 256;
        int row = idx / DIM, colf = idx - row * DIM;
        float v = a[(size_t)(n0 + row) * DIM + colf];
        sH[row * 21 + colf] = fmaxf(v * sS[colf] + sS[DIM + colf], 0.0f);
    }
    __syncthreads();
    int nl = tid & 63, wq = tid >> 6;
    float acc[5] = {0.f, 0.f, 0.f, 0.f, 0.f};
    for (int f = 0; f < DIM; ++f) {
        float h = sH[nl * 21 + f];
        #pragma unroll
        for (int k = 0; k < 5; ++k) acc[k] += h * sW[f * DIM + wq + 4 * k];
    }
    float dv = dinv[n0 + nl];
    #pragma unroll
    for (int k = 0; k < 5; ++k) sO[nl * 32 + wq + 4 * k] = f2bf(acc[k] * dv);
    __syncthreads();
    if (tid < 192) {
        int row = tid / 3, part = tid - row * 3;
        ((uint4*)(yb + (size_t)(n0 + row) * 32))[part] = ((const uint4*)(sO + row * 32))[part];
    }
}

// ---------------- final (BN folded): relu(bn) -> emb + segment_max ----------------
__global__ __launch_bounds__(256) void final_kernel(const float* __restrict__ a, const float* __restrict__ stats,
                                                    const float* __restrict__ g, const float* __restrict__ beta,
                                                    const int* __restrict__ batch, float* __restrict__ emb,
                                                    unsigned int* __restrict__ ge) {
    __shared__ unsigned int lmax[8 * DIM];
    __shared__ float sS[2 * DIM];
    __shared__ int sg[2];
    int tid = threadIdx.x;
    if (tid < DIM) {
        float mean = stats[tid] * (1.0f / NN);
        float var = stats[DIM + tid] * (1.0f / NN) - mean * mean;
        float sc = g[tid] * rsqrtf(var + BN_EPS);
        sS[tid] = sc;
        sS[DIM + tid] = beta[tid] - mean * sc;
    }
    int n0 = blockIdx.x * 256;
    if (tid == 0) {
        int nlast = min(n0 + 255, NN - 1);
        sg[0] = batch[n0];
        sg[1] = batch[nlast] - batch[n0] + 1;
    }
    for (int i = tid; i < 8 * DIM; i += 256) lmax[i] = 0u;
    __syncthreads();
    int gmin = sg[0], gspan = sg[1];
    bool uselds = (gspan <= 8);
    int n = n0 + tid;
    if (n < NN) {
        int g2 = batch[n];
        float vals[DIM];
        const float4* ar = (const float4*)(a + (size_t)n * DIM);
        float4* er = (float4*)(emb + (size_t)n * DIM);
        #pragma unroll
        for (int c = 0; c < 5; ++c) {
            float4 v = ar[c];
            float r0 = fmaxf(v.x * sS[4*c+0] + sS[DIM + 4*c+0], 0.0f);
            float r1 = fmaxf(v.y * sS[4*c+1] + sS[DIM + 4*c+1], 0.0f);
            float r2 = fmaxf(v.z * sS[4*c+2] + sS[DIM + 4*c+2], 0.0f);
            float r3 = fmaxf(v.w * sS[4*c+3] + sS[DIM + 4*c+3], 0.0f);
            er[c] = make_float4(r0, r1, r2, r3);
            vals[4*c+0] = r0; vals[4*c+1] = r1; vals[4*c+2] = r2; vals[4*c+3] = r3;
        }
        if (uselds) {
            int base = (g2 - gmin) * DIM;
            #pragma unroll
            for (int jo = 0; jo < DIM; ++jo) {
                int j = (jo + tid) % DIM;
                atomicMax(&lmax[base + j], __float_as_uint(vals[j]));
            }
        } else {
            #pragma unroll
            for (int jo = 0; jo < DIM; ++jo) {
                int j = (jo + tid) % DIM;
                atomicMax(&ge[g2 * DIM + j], __float_as_uint(vals[j]));
            }
        }
    }
    __syncthreads();
    if (uselds) {
        for (int i = tid; i < gspan * DIM; i += 256) {
            unsigned int v = lmax[i];
            if (v) atomicMax(&ge[gmin * DIM + i], v);
        }
    }
}

// ---------------- fc head ----------------
__global__ __launch_bounds__(256) void fc_kernel(const float* __restrict__ ge, const float* __restrict__ fcW,
                                                 const float* __restrict__ fcb, float* __restrict__ out) {
    int gid = blockIdx.x * 256 + threadIdx.x;
    if (gid >= NGR * NCL) return;
    int g = gid >> 1, c = gid & 1;
    float acc = fcb[c];
    #pragma unroll
    for (int d = 0; d < DIM; ++d) acc += ge[g * DIM + d] * fcW[d * NCL + c];
    out[gid] = acc;
}

extern "C" void kernel_launch(void* const* d_in, const int* in_sizes, int n_in,
                              void* d_out, int out_size, void* d_ws, size_t ws_size,
                              hipStream_t stream) {
    const float* x     = (const float*)d_in[0];
    const int*   ei    = (const int*)d_in[1];
    const int*   src   = ei;
    const int*   dst   = ei + NE;
    const int*   batch = (const int*)d_in[2];
    const float* W0 = (const float*)d_in[3];  const float* b0 = (const float*)d_in[4];
    const float* g0 = (const float*)d_in[5];  const float* be0 = (const float*)d_in[6];
    const float* W1 = (const float*)d_in[7];  const float* b1 = (const float*)d_in[8];
    const float* g1 = (const float*)d_in[9];  const float* be1 = (const float*)d_in[10];
    const float* W2 = (const float*)d_in[11]; const float* b2 = (const float*)d_in[12];
    const float* g2 = (const float*)d_in[13]; const float* be2 = (const float*)d_in[14];
    const float* fcW = (const float*)d_in[15]; const float* fcb = (const float*)d_in[16];

    float* ws = (float*)d_ws;
    float* dinv     = ws;                               // NN
    int*   rowstart = (int*)(ws + NN);                  // NN (exclusive row ends)
    float* stats    = ws + 2 * NN;                      // 192
    int*   ghist    = (int*)(stats + 192);              // NCTR
    int*   bbase    = ghist + NCTR;                     // NCTR+1
    int*   bcur     = bbase + NCTR + 1;                 // NCTR
    float* agg      = ws + 409700;                      // NN*DIM fp32; aliases packed[]
    unsigned int* packed = (unsigned int*)agg;          // NE u32 == NN*DIM
    ushort_t* ybuf  = (ushort_t*)(ws + 4409712);        // NN rows x 64B
    int*   col      = (int*)(ws + 4409712 + (size_t)NN * 16);   // NE ints

    float* emb    = (float*)d_out;                      // NN*DIM
    float* ge     = emb + (size_t)NN * DIM;             // NGR*DIM
    float* logits = ge + NGR * DIM;                     // NGR*NCL

    const int N_BLKS = (NN + 255) / 256;                // 782
    const int L_BLKS = NN / 64;                         // 3125 (linears)
    const int G_BLKS = (NN + 127) / 128;                // 1563 (gather)

    hipMemsetAsync(ghist, 0, NCTR * sizeof(int), stream);
    hipMemsetAsync(stats, 0, 192 * sizeof(float), stream);
    hipMemsetAsync(ge, 0, NGR * DIM * sizeof(float), stream);

    // ---- CSR build: two-level multisplit, (dst_low, src_slice)-sorted segments ----
    hist_kernel<<<NT2, 256, 0, stream>>>(dst, ghist);
    scan_small_kernel<<<1, 1024, 0, stream>>>(ghist, bbase, bcur);
    p2_kernel<<<NT2, 256, 0, stream>>>(src, dst, bcur, packed);
    p3_kernel<<<BKT, 256, 0, stream>>>(packed, bbase, col, rowstart, dinv);

    lin0_kernel<<<L_BLKS, 256, 0, stream>>>(x, W0, dinv, ybuf);   // packed dead after p3

    gather_kernel<<<G_BLKS, 256, 0, stream>>>(ybuf, col, rowstart, dinv, b0, agg, stats);
    lin_next_kernel<<<L_BLKS, 256, 0, stream>>>(agg, stats, g0, be0, W1, dinv, ybuf);

    gather_kernel<<<G_BLKS, 256, 0, stream>>>(ybuf, col, rowstart, dinv, b1, agg, stats + 64);
    lin_next_kernel<<<L_BLKS, 256, 0, stream>>>(agg, stats + 64, g1, be1, W2, dinv, ybuf);

    gather_kernel<<<G_BLKS, 256, 0, stream>>>(ybuf, col, rowstart, dinv, b2, agg, stats + 128);

    final_kernel<<<N_BLKS, 256, 0, stream>>>(agg, stats + 128, g2, be2, batch, emb, (unsigned int*)ge);
    fc_kernel<<<(NGR * NCL + 255) / 256, 256, 0, stream>>>(ge, fcW, fcb, logits);
}